// Round 12
// baseline (731.053 us; speedup 1.0000x reference)
//
#include <hip/hip_runtime.h>
#include <stdint.h>

typedef unsigned int u32;
using i32x4 = __attribute__((ext_vector_type(4))) int;

// async global->LDS, 16B per lane, dest = wave-uniform base + lane*16
#define GLD_LDS16(SRC, DST)                                      \
  __builtin_amdgcn_global_load_lds(                              \
      (const __attribute__((address_space(1))) void*)(SRC),      \
      (__attribute__((address_space(3))) void*)(DST), 16, 0, 0)

#define SCHED0() __builtin_amdgcn_sched_barrier(0)
#define BAR()    __builtin_amdgcn_s_barrier()
#define PRIO(x)  __builtin_amdgcn_s_setprio(x)

// ---------- pass 1: per-row symmetric int8 quant (x rows, then w rows) ----------
__global__ __launch_bounds__(256)
void quant_rows(const float* __restrict__ x, const float* __restrict__ w,
                signed char* __restrict__ xq, signed char* __restrict__ wq,
                float* __restrict__ sx, float* __restrict__ sw,
                int Mrows, int totRows, int K) {
  __shared__ float red[4];
  for (int row = blockIdx.x; row < totRows; row += gridDim.x) {
    const bool isx = row < Mrows;
    const float* src = isx ? x + (size_t)row * K : w + (size_t)(row - Mrows) * K;
    const float4* s4 = reinterpret_cast<const float4*>(src) + threadIdx.x * 4;
    float4 v[4];
#pragma unroll
    for (int g = 0; g < 4; ++g) v[g] = s4[g];
    float am = 0.f;
#pragma unroll
    for (int g = 0; g < 4; ++g)
      am = fmaxf(am, fmaxf(fmaxf(fabsf(v[g].x), fabsf(v[g].y)),
                           fmaxf(fabsf(v[g].z), fabsf(v[g].w))));
#pragma unroll
    for (int m = 1; m <= 32; m <<= 1) am = fmaxf(am, __shfl_xor(am, m));
    if ((threadIdx.x & 63) == 0) red[threadIdx.x >> 6] = am;
    __syncthreads();
    am = fmaxf(fmaxf(red[0], red[1]), fmaxf(red[2], red[3]));
    const float s   = am > 0.f ? am * (1.f / 127.f) : 1.f;
    const float inv = am > 0.f ? 127.f / am : 0.f;
    u32 pk[4];
#pragma unroll
    for (int g = 0; g < 4; ++g) {
      const float* vp = reinterpret_cast<const float*>(&v[g]);
      u32 p = 0;
#pragma unroll
      for (int e = 0; e < 4; ++e) {
        int q = (int)rintf(vp[e] * inv);
        q = q < -127 ? -127 : (q > 127 ? 127 : q);
        p |= ((u32)(q & 0xff)) << (8 * e);
      }
      pk[g] = p;
    }
    signed char* dst = (isx ? xq + (size_t)row * K : wq + (size_t)(row - Mrows) * K)
                       + threadIdx.x * 16;
    *reinterpret_cast<uint4*>(dst) = make_uint4(pk[0], pk[1], pk[2], pk[3]);
    if (threadIdx.x == 0) { if (isx) sx[row] = s; else sw[row - Mrows] = s; }
    __syncthreads();
  }
}

// ---------- pass 2: int8 GEMM, 4 waves x 128x128 output each (redundancy-min) ----------
// BM=BN=256, BK=128, 4 waves (2M x 2N), 1 wave/SIMD, acc[8][8] i32x4 = 256 regs/wave
// (legal at launch_bounds(256,1): ~512-reg budget, no-spill through ~450 per m08).
// LDS-read redundancy drops 192KB -> 128KB per CU-tile (square wave tile minimizes
// (waveM+waveN)*BK). Swizzle/addressing byte-identical to verified r9 (0 conflicts,
// absmax bit-stable). 8 clusters of 16 MFMA per tile; operands read >=1 cluster ahead.
//   R1: BAR | C1(aF*bF) rd bG(n1k0) | C2(aF*bG) rd aG(m1k0) | C3(aG*bF) rd aF(m0k1)
//       | C4(aG*bG) rd bF(n0k1) | C5(aF*bF) rd bG(n1k1) | C6(aF*bG) rd aG(m1k1)
//       | vmcnt(8)   <- drains A(t+1), staged t-1 R2 (~1 tile old)
//   R2: BAR | stage A(t+2)->cur, B(t+2)->cur | rd aF<-A(t+1,m0,k0) | C7(aG*bF)
//       | vmcnt(16)  <- drains B(t+1)        | rd bF<-B(t+1,n0,k0) | C8(aG*bG)
// Ledger (per wave, 16 gloads/tile all in R2, A then B): R1-entry outstanding =
// {A(t+1):8, B(t+1):8}; g1=vmcnt(8) drains A(t+1). R2 after stage: {B(t+1):8,
// A(t+2):8, B(t+2):8}=24; g2=vmcnt(16) drains B(t+1). Cross-wave visibility: each
// gate is followed by a BAR before any other wave's staged data is ds_read.
// WAR: aF re-read after C6 (dead), bF after C7, bG/aG after C8; stage->cur regions
// (A,B of t+2) overwrite data last ds_read in R1, separated by R2's BAR.
__global__ __launch_bounds__(256, 1)
void gemm_i8_sq(const signed char* __restrict__ A,   // [M][K] i8
                const signed char* __restrict__ B,   // [N][K] i8
                const float* __restrict__ sx,        // [M]
                const float* __restrict__ sw,        // [N]
                const float* __restrict__ wscale_p,  // [1]
                const float* __restrict__ bias,      // [N]
                float* __restrict__ C,               // [M][N] fp32
                int Nn, int Kk, int NT) {
  __shared__ signed char lds[2][2][256 * 128];  // 128 KiB

  const int tid  = threadIdx.x;
  const int lane = tid & 63;
  const int wave = tid >> 6;       // 0..3
  const int wr = wave >> 1;        // 0..1 (M)
  const int wc = wave & 1;         // 0..1 (N)

  // T1: XCD-aware swizzle (gridDim.x == 2048, divisible by 8)
  const int bid = blockIdx.x;
  const int cpx = gridDim.x >> 3;
  const int wg  = (bid & 7) * cpx + (bid >> 3);
  const int mt = wg / NT, nt = wg % NT;
  const int m0 = mt * 256, n0 = nt * 256;

  // staging: per gload instr, 64 lanes = 8 rows x 128B; lane l -> row l>>3, slot l&7
  const int srow = lane >> 3;
  const int ss   = (lane & 7) ^ (srow & 7);   // inverse-swizzled source k-slot
  const int r16  = lane & 15;
  const int kq   = lane >> 4;

  // per-wave staging slice: 64 rows (8 gloads x 8 rows) of A and of B
  const signed char* ga = A + ((size_t)m0 + wave * 64 + srow) * Kk + ss * 16;
  const signed char* gb = B + ((size_t)n0 + wave * 64 + srow) * Kk + ss * 16;

  // fragment byte offsets: row*128 + ((kq ^ (row&7))<<4); ks=1 flips byte bit 6
  const int aoff = (wr * 128 + r16) * 128 + ((kq ^ (r16 & 7)) << 4);
  const int boff = (wc * 128 + r16) * 128 + ((kq ^ (r16 & 7)) << 4);

  i32x4 acc[8][8];
#pragma unroll
  for (int i = 0; i < 8; ++i)
#pragma unroll
    for (int j = 0; j < 8; ++j)
      acc[i][j] = (i32x4){0, 0, 0, 0};

  i32x4 aF[4], aG[4];   // A frag halves (mh0 / mh1 roles, rotating ks)
  i32x4 bF[4], bG[4];   // B frag halves (nh0 / nh1 roles, rotating ks)

  // stage one operand tile slice (8KB, 8 gloads): op (0=A,1=B) -> lds[bfi], k-tile kt
#define STAGE8(bfi_, op_, kt_) do {                                             \
    const signed char* _g = ((op_) ? gb : ga) + (size_t)(kt_) * 128;            \
    signed char* _d = &lds[bfi_][op_][wave * 64 * 128];                         \
    _Pragma("unroll") for (int _j = 0; _j < 8; ++_j)                            \
      GLD_LDS16(_g + (size_t)(_j * 8) * Kk, _d + _j * 1024);                    \
  } while (0)

#define LDF_A(AF_, la_, mh_, ks_) do {                                          \
    _Pragma("unroll") for (int _i = 0; _i < 4; ++_i)                            \
      AF_[_i] = *reinterpret_cast<const i32x4*>(                                \
          (la_) + ((aoff + ((mh_) * 4 + _i) * 2048) ^ ((ks_) << 6)));           \
  } while (0)

#define LDF_B(BF_, lb_, nh_, ks_) do {                                          \
    _Pragma("unroll") for (int _n = 0; _n < 4; ++_n)                            \
      BF_[_n] = *reinterpret_cast<const i32x4*>(                                \
          (lb_) + ((boff + ((nh_) * 4 + _n) * 2048) ^ ((ks_) << 6)));           \
  } while (0)

#define MFMAC(mh_, nh_, AF_, BF_)                                               \
  _Pragma("unroll") for (int i = 0; i < 4; ++i)                                 \
  _Pragma("unroll") for (int n = 0; n < 4; ++n)                                 \
    acc[(mh_) * 4 + i][(nh_) * 4 + n] = __builtin_amdgcn_mfma_i32_16x16x64_i8(  \
        AF_[i], BF_[n], acc[(mh_) * 4 + i][(nh_) * 4 + n], 0, 0, 0)

  const int KT = Kk >> 7;   // K/128 = 32

  // ---- prologue: t0 (A,B) -> buf0; t1 A then B -> buf1; drain t0; pre-read ----
  STAGE8(0, 0, 0); STAGE8(0, 1, 0);
  STAGE8(1, 0, 1); STAGE8(1, 1, 1);
  asm volatile("s_waitcnt vmcnt(16)" ::: "memory");
  SCHED0(); BAR(); SCHED0();
  LDF_A(aF, (const signed char*)&lds[0][0][0], 0, 0);
  LDF_B(bF, (const signed char*)&lds[0][1][0], 0, 0);

#define TILE(t_, CUR_) do {                                                     \
    const signed char* laC = &lds[CUR_][0][0];                                  \
    const signed char* lbC = &lds[CUR_][1][0];                                  \
    const signed char* laN = &lds[(CUR_) ^ 1][0][0];                            \
    const signed char* lbN = &lds[(CUR_) ^ 1][1][0];                            \
    const int kt2 = ((t_) + 2 < KT) ? (t_) + 2 : KT - 1;                        \
    /* ---- region 1: C1..C6, all cur-buf reads ---- */                         \
    SCHED0(); BAR(); SCHED0();                                                  \
    PRIO(1); MFMAC(0, 0, aF, bF); PRIO(0);    /* C1: m0 x n0, k0 */             \
    LDF_B(bG, lbC, 1, 0);                                                       \
    PRIO(1); MFMAC(0, 1, aF, bG); PRIO(0);    /* C2: m0 x n1, k0 */             \
    LDF_A(aG, laC, 1, 0);                                                       \
    PRIO(1); MFMAC(1, 0, aG, bF); PRIO(0);    /* C3: m1 x n0, k0 */             \
    LDF_A(aF, laC, 0, 1);                                                       \
    PRIO(1); MFMAC(1, 1, aG, bG); PRIO(0);    /* C4: m1 x n1, k0 */             \
    LDF_B(bF, lbC, 0, 1);                                                       \
    PRIO(1); MFMAC(0, 0, aF, bF); PRIO(0);    /* C5: m0 x n0, k1 */             \
    LDF_B(bG, lbC, 1, 1);                                                       \
    PRIO(1); MFMAC(0, 1, aF, bG); PRIO(0);    /* C6: m0 x n1, k1 */             \
    LDF_A(aG, laC, 1, 1);                                                       \
    SCHED0();                                                                   \
    asm volatile("s_waitcnt vmcnt(8)" ::: "memory");   /* A(t+1) landed */      \
    /* ---- region 2: stage t+2, finish k1, pre-read t+1 ---- */                \
    SCHED0(); BAR(); SCHED0();                                                  \
    STAGE8(CUR_, 0, kt2);                     /* A(t+2)->cur */                 \
    STAGE8(CUR_, 1, kt2);                     /* B(t+2)->cur */                 \
    LDF_A(aF, laN, 0, 0);                     /* A(t+1) m0 k0 */                \
    PRIO(1); MFMAC(1, 0, aG, bF); PRIO(0);    /* C7: m1 x n0, k1 */             \
    SCHED0();                                                                   \
    asm volatile("s_waitcnt vmcnt(16)" ::: "memory");  /* B(t+1) landed */      \
    SCHED0();                                                                   \
    LDF_B(bF, lbN, 0, 0);                     /* B(t+1) n0 k0 */                \
    PRIO(1); MFMAC(1, 1, aG, bG); PRIO(0);    /* C8: m1 x n1, k1 */             \
  } while (0)

  for (int t = 0; t < KT; t += 2) {
    TILE(t,     0);
    TILE(t + 1, 1);
  }

  // ---- epilogue: out = acc * sx[row] * (sw[col]*wscale) + bias ----
  const float wsc = wscale_p[0];
  float cw[8], bv[8];
#pragma unroll
  for (int ni = 0; ni < 8; ++ni) {
    const int col = n0 + wc * 128 + ni * 16 + r16;
    cw[ni] = sw[col] * wsc;
    bv[ni] = bias[col];
  }
#pragma unroll
  for (int mi = 0; mi < 8; ++mi) {
#pragma unroll
    for (int r = 0; r < 4; ++r) {
      // C/D layout (16x16 shapes, dtype-independent): col = lane&15, row = (lane>>4)*4 + reg
      const int row = m0 + wr * 128 + mi * 16 + kq * 4 + r;
      const float sxr = sx[row];
      float* cp = C + (size_t)row * Nn + (n0 + wc * 128 + r16);
#pragma unroll
      for (int ni = 0; ni < 8; ++ni)
        cp[ni * 16] = (float)acc[mi][ni][r] * (sxr * cw[ni]) + bv[ni];
    }
  }
#undef STAGE8
#undef LDF_A
#undef LDF_B
#undef MFMAC
#undef TILE
}

extern "C" void kernel_launch(void* const* d_in, const int* in_sizes, int n_in,
                              void* d_out, int out_size, void* d_ws, size_t ws_size,
                              hipStream_t stream) {
  (void)n_in; (void)out_size; (void)ws_size;
  const float* x  = (const float*)d_in[0];   // [M][K] fp32
  const float* w  = (const float*)d_in[1];   // [N][K] fp32 (fp8-representable values)
  const float* sc = (const float*)d_in[2];   // [1]
  const float* bs = (const float*)d_in[3];   // [N]
  float* out = (float*)d_out;                // [M][N] fp32

  const int N = in_sizes[3];        // 16384
  const int K = in_sizes[1] / N;    // 4096
  const int M = in_sizes[0] / K;    // 8192

  signed char* xq = (signed char*)d_ws;            // [M][K] i8  (32 MB)
  signed char* wq = xq + (size_t)M * K;            // [N][K] i8  (64 MB)
  float* sxp = (float*)(wq + (size_t)N * K);       // [M]
  float* swp = sxp + M;                            // [N]

  quant_rows<<<M + N, 256, 0, stream>>>(x, w, xq, wq, sxp, swp, M, M + N, K);

  const int NT = N / 256;
  const int nwg = (M / 256) * NT;                  // 2048, % 8 == 0
  gemm_i8_sq<<<nwg, 256, 0, stream>>>(xq, wq, sxp, swp, sc, bs, out, N, K, NT);
}

// Round 13
// 644.418 us; speedup vs baseline: 1.1344x; 1.1344x over previous
//
#include <hip/hip_runtime.h>
#include <stdint.h>

typedef unsigned int u32;
using i32x4 = __attribute__((ext_vector_type(4))) int;

// async global->LDS, 16B per lane, dest = wave-uniform base + lane*16
#define GLD_LDS16(SRC, DST)                                      \
  __builtin_amdgcn_global_load_lds(                              \
      (const __attribute__((address_space(1))) void*)(SRC),      \
      (__attribute__((address_space(3))) void*)(DST), 16, 0, 0)

#define SCHED0() __builtin_amdgcn_sched_barrier(0)
#define BAR()    __builtin_amdgcn_s_barrier()

// ---------- pass 1: per-row symmetric int8 quant (x rows, then w rows) ----------
__global__ __launch_bounds__(256)
void quant_rows(const float* __restrict__ x, const float* __restrict__ w,
                signed char* __restrict__ xq, signed char* __restrict__ wq,
                float* __restrict__ sx, float* __restrict__ sw,
                int Mrows, int totRows, int K) {
  __shared__ float red[4];
  for (int row = blockIdx.x; row < totRows; row += gridDim.x) {
    const bool isx = row < Mrows;
    const float* src = isx ? x + (size_t)row * K : w + (size_t)(row - Mrows) * K;
    const float4* s4 = reinterpret_cast<const float4*>(src) + threadIdx.x * 4;
    float4 v[4];
#pragma unroll
    for (int g = 0; g < 4; ++g) v[g] = s4[g];
    float am = 0.f;
#pragma unroll
    for (int g = 0; g < 4; ++g)
      am = fmaxf(am, fmaxf(fmaxf(fabsf(v[g].x), fabsf(v[g].y)),
                           fmaxf(fabsf(v[g].z), fabsf(v[g].w))));
#pragma unroll
    for (int m = 1; m <= 32; m <<= 1) am = fmaxf(am, __shfl_xor(am, m));
    if ((threadIdx.x & 63) == 0) red[threadIdx.x >> 6] = am;
    __syncthreads();
    am = fmaxf(fmaxf(red[0], red[1]), fmaxf(red[2], red[3]));
    const float s   = am > 0.f ? am * (1.f / 127.f) : 1.f;
    const float inv = am > 0.f ? 127.f / am : 0.f;
    u32 pk[4];
#pragma unroll
    for (int g = 0; g < 4; ++g) {
      const float* vp = reinterpret_cast<const float*>(&v[g]);
      u32 p = 0;
#pragma unroll
      for (int e = 0; e < 4; ++e) {
        int q = (int)rintf(vp[e] * inv);
        q = q < -127 ? -127 : (q > 127 ? 127 : q);
        p |= ((u32)(q & 0xff)) << (8 * e);
      }
      pk[g] = p;
    }
    signed char* dst = (isx ? xq + (size_t)row * K : wq + (size_t)(row - Mrows) * K)
                       + threadIdx.x * 16;
    *reinterpret_cast<uint4*>(dst) = make_uint4(pk[0], pk[1], pk[2], pk[3]);
    if (threadIdx.x == 0) { if (isx) sx[row] = s; else sw[row - Mrows] = s; }
    __syncthreads();
  }
}

// ---------- pass 2: int8 GEMM BK=128, DEEP READ-AHEAD tile ----------
// Geometry/swizzle/addressing identical to verified r9 (absmax bit-stable
// 0.1015625, 0 bank conflicts): 256x256 tile, 8 waves (2Mx4N), 128x64/wave,
// 16x16x64 frags, LDS [2][2][256*128] = 128 KiB.
// NEW tile structure (the anti-serial fix): per tile, issue ALL 24 ds_read_b128
// FIRST (frag regs af[16], bf[8] = 96 VGPR live), then ALL 64 MFMAs (compiler
// emits progressive lgkmcnt(N) gates), then stage(t+2)->cur, then aged vmcnt(8).
// In-order issue now fills the LDS pipe's whole 2304-cyc queue up front, so it
// drains WHILE the matrix pipe runs its 2612 cyc -> pipes overlap instead of
// serializing. 1 barrier/tile. No setprio (would starve co-wave's read issue).
// WAR: stage issues after the wave's MFMA block (>=2600 cyc post-BAR issue,
// +>=200 cyc landing > 2304-cyc worst-case LDS drain of ALL waves' tile reads).
// Gate ledger: end of tile t outstanding = {t+1:8, t+2:8}; vmcnt(8) drains t+1
// (issued one full tile ~3000 cyc ago); next BAR publishes cross-wave.
__global__ __launch_bounds__(512, 2)
void gemm_i8_deep(const signed char* __restrict__ A,   // [M][K] i8
                  const signed char* __restrict__ B,   // [N][K] i8
                  const float* __restrict__ sx,        // [M]
                  const float* __restrict__ sw,        // [N]
                  const float* __restrict__ wscale_p,  // [1]
                  const float* __restrict__ bias,      // [N]
                  float* __restrict__ C,               // [M][N] fp32
                  int Nn, int Kk, int NT) {
  __shared__ signed char lds[2][2][256 * 128];

  const int tid  = threadIdx.x;
  const int lane = tid & 63;
  const int wave = tid >> 6;       // 0..7
  const int wr = wave >> 2;        // 0..1 (M)
  const int wc = wave & 3;         // 0..3 (N)

  // T1: XCD-aware swizzle (gridDim.x == 2048, divisible by 8)
  const int bid = blockIdx.x;
  const int cpx = gridDim.x >> 3;
  const int wg  = (bid & 7) * cpx + (bid >> 3);
  const int mt = wg / NT, nt = wg % NT;
  const int m0 = mt * 256, n0 = nt * 256;

  // staging: per gload instr, 64 lanes = 8 rows x 128B; lane l -> row l>>3, slot l&7
  const int srow = lane >> 3;
  const int ss   = (lane & 7) ^ (srow & 7);   // inverse-swizzled source k-slot
  const int r16  = lane & 15;
  const int kq   = lane >> 4;

  const signed char* ga = A + ((size_t)m0 + wave * 32 + srow) * Kk + ss * 16;
  const signed char* gb = B + ((size_t)n0 + wave * 32 + srow) * Kk + ss * 16;

  // fragment byte offsets: row*128 + ((kq ^ (row&7))<<4). ks=1 flips byte bit 6;
  // since bits 0-3 of aoff are 0 and frag-steps are multiples of 2048, the XOR
  // folds into a second base: (aoff + f*2048)^64 == (aoff^64) + f*2048.
  const int aoff = (wr * 128 + r16) * 128 + ((kq ^ (r16 & 7)) << 4);
  const int boff = (wc * 64  + r16) * 128 + ((kq ^ (r16 & 7)) << 4);

  i32x4 acc[8][4];
#pragma unroll
  for (int i = 0; i < 8; ++i)
#pragma unroll
    for (int j = 0; j < 4; ++j)
      acc[i][j] = (i32x4){0, 0, 0, 0};

  i32x4 af[16];   // A frags: [mh0 ks0: 0-3][mh1 ks0: 4-7][mh0 ks1: 8-11][mh1 ks1: 12-15]
  i32x4 bf[8];    // B frags: [ks0: 0-3][ks1: 4-7]

#define STAGE128(bfi_, op_, kt_) do {                                           \
    const signed char* _g = ((op_) ? gb : ga) + (size_t)(kt_) * 128;            \
    signed char* _d = &lds[bfi_][op_][wave * 32 * 128];                         \
    GLD_LDS16(_g,                    _d);                                       \
    GLD_LDS16(_g + (size_t)8  * Kk,  _d + 1024);                                \
    GLD_LDS16(_g + (size_t)16 * Kk,  _d + 2048);                                \
    GLD_LDS16(_g + (size_t)24 * Kk,  _d + 3072);                                \
  } while (0)

  // full tile read block: 24 ds_read_b128, ordered so cluster c's operands are
  // among the first 8(c+1) reads (smooth progressive lgkmcnt gating).
#define READ24(la_, lb_) do {                                                   \
    const signed char* _la0 = (la_) + aoff;                                     \
    const signed char* _la1 = (la_) + (aoff ^ 64);                              \
    const signed char* _lb0 = (lb_) + boff;                                     \
    const signed char* _lb1 = (lb_) + (boff ^ 64);                              \
    _Pragma("unroll") for (int _n = 0; _n < 4; ++_n)                            \
      bf[_n]      = *reinterpret_cast<const i32x4*>(_lb0 + _n * 2048);          \
    _Pragma("unroll") for (int _i = 0; _i < 4; ++_i)                            \
      af[_i]      = *reinterpret_cast<const i32x4*>(_la0 + _i * 2048);          \
    _Pragma("unroll") for (int _i = 0; _i < 4; ++_i)                            \
      af[4 + _i]  = *reinterpret_cast<const i32x4*>(_la0 + (4 + _i) * 2048);    \
    _Pragma("unroll") for (int _n = 0; _n < 4; ++_n)                            \
      bf[4 + _n]  = *reinterpret_cast<const i32x4*>(_lb1 + _n * 2048);          \
    _Pragma("unroll") for (int _i = 0; _i < 4; ++_i)                            \
      af[8 + _i]  = *reinterpret_cast<const i32x4*>(_la1 + _i * 2048);          \
    _Pragma("unroll") for (int _i = 0; _i < 4; ++_i)                            \
      af[12 + _i] = *reinterpret_cast<const i32x4*>(_la1 + (4 + _i) * 2048);    \
  } while (0)

  // full tile MFMA block: 64 MFMAs in 4 clusters (mh0ks0, mh1ks0, mh0ks1, mh1ks1)
#define MFMA64() do {                                                           \
    _Pragma("unroll") for (int _i = 0; _i < 4; ++_i)                            \
    _Pragma("unroll") for (int _n = 0; _n < 4; ++_n)                            \
      acc[_i][_n] = __builtin_amdgcn_mfma_i32_16x16x64_i8(                      \
          af[_i], bf[_n], acc[_i][_n], 0, 0, 0);                                \
    _Pragma("unroll") for (int _i = 0; _i < 4; ++_i)                            \
    _Pragma("unroll") for (int _n = 0; _n < 4; ++_n)                            \
      acc[4 + _i][_n] = __builtin_amdgcn_mfma_i32_16x16x64_i8(                  \
          af[4 + _i], bf[_n], acc[4 + _i][_n], 0, 0, 0);                        \
    _Pragma("unroll") for (int _i = 0; _i < 4; ++_i)                            \
    _Pragma("unroll") for (int _n = 0; _n < 4; ++_n)                            \
      acc[_i][_n] = __builtin_amdgcn_mfma_i32_16x16x64_i8(                      \
          af[8 + _i], bf[4 + _n], acc[_i][_n], 0, 0, 0);                        \
    _Pragma("unroll") for (int _i = 0; _i < 4; ++_i)                            \
    _Pragma("unroll") for (int _n = 0; _n < 4; ++_n)                            \
      acc[4 + _i][_n] = __builtin_amdgcn_mfma_i32_16x16x64_i8(                  \
          af[12 + _i], bf[4 + _n], acc[4 + _i][_n], 0, 0, 0);                   \
  } while (0)

  const int KT = Kk >> 7;   // K/128 = 32

  // ---- prologue: t0 -> buf0 (8 gloads), t1 -> buf1 (8); drain t0 ----
  STAGE128(0, 0, 0); STAGE128(0, 1, 0);
  STAGE128(1, 0, 1); STAGE128(1, 1, 1);
  asm volatile("s_waitcnt vmcnt(8)" ::: "memory");

#define TILE(t_, CUR_) do {                                                     \
    const int kt2 = ((t_) + 2 < KT) ? (t_) + 2 : KT - 1;                        \
    SCHED0(); BAR(); SCHED0();                                                  \
    READ24((const signed char*)&lds[CUR_][0][0],                                \
           (const signed char*)&lds[CUR_][1][0]);                               \
    SCHED0();                                                                   \
    MFMA64();                                                                   \
    SCHED0();                                                                   \
    STAGE128(CUR_, 0, kt2);                                                     \
    STAGE128(CUR_, 1, kt2);                                                     \
    asm volatile("s_waitcnt vmcnt(8)" ::: "memory");  /* drains t+1 (1 tile old) */ \
  } while (0)

  for (int t = 0; t < KT; t += 2) {
    TILE(t,     0);
    TILE(t + 1, 1);
  }

  // ---- epilogue: out = acc * sx[row] * (sw[col]*wscale) + bias ----
  const float wsc = wscale_p[0];
  float cw[4], bv[4];
#pragma unroll
  for (int ni = 0; ni < 4; ++ni) {
    const int col = n0 + wc * 64 + ni * 16 + r16;
    cw[ni] = sw[col] * wsc;
    bv[ni] = bias[col];
  }
#pragma unroll
  for (int mi = 0; mi < 8; ++mi) {
#pragma unroll
    for (int r = 0; r < 4; ++r) {
      // C/D layout (16x16 shapes, dtype-independent): col = lane&15, row = (lane>>4)*4 + reg
      const int row = m0 + wr * 128 + mi * 16 + kq * 4 + r;
      const float sxr = sx[row];
      float* cp = C + (size_t)row * Nn + (n0 + wc * 64 + r16);
#pragma unroll
      for (int ni = 0; ni < 4; ++ni)
        cp[ni * 16] = (float)acc[mi][ni][r] * (sxr * cw[ni]) + bv[ni];
    }
  }
#undef STAGE128
#undef READ24
#undef MFMA64
#undef TILE
}

extern "C" void kernel_launch(void* const* d_in, const int* in_sizes, int n_in,
                              void* d_out, int out_size, void* d_ws, size_t ws_size,
                              hipStream_t stream) {
  (void)n_in; (void)out_size; (void)ws_size;
  const float* x  = (const float*)d_in[0];   // [M][K] fp32
  const float* w  = (const float*)d_in[1];   // [N][K] fp32 (fp8-representable values)
  const float* sc = (const float*)d_in[2];   // [1]
  const float* bs = (const float*)d_in[3];   // [N]
  float* out = (float*)d_out;                // [M][N] fp32

  const int N = in_sizes[3];        // 16384
  const int K = in_sizes[1] / N;    // 4096
  const int M = in_sizes[0] / K;    // 8192

  signed char* xq = (signed char*)d_ws;            // [M][K] i8  (32 MB)
  signed char* wq = xq + (size_t)M * K;            // [N][K] i8  (64 MB)
  float* sxp = (float*)(wq + (size_t)N * K);       // [M]
  float* swp = sxp + M;                            // [N]

  quant_rows<<<M + N, 256, 0, stream>>>(x, w, xq, wq, sxp, swp, M, M + N, K);

  const int NT = N / 256;
  const int nwg = (M / 256) * NT;                  // 2048, % 8 == 0
  gemm_i8_deep<<<nwg, 512, 0, stream>>>(xq, wq, sxp, swp, sc, bs, out, N, K, NT);
}